// Round 4
// baseline (163.525 us; speedup 1.0000x reference)
//
#include <hip/hip_runtime.h>
#include <cstdint>

typedef float  f32x16 __attribute__((ext_vector_type(16)));
typedef short  s16x8  __attribute__((ext_vector_type(8)));

__device__ __forceinline__ unsigned short f2bf(float f){
  unsigned int u = __float_as_uint(f);
  return (unsigned short)((u + 0x7FFFu + ((u >> 16) & 1u)) >> 16);   // RNE
}

// g_Wt[tap][o][ci] bf16, tap = kh*3+kw : W[o][ci][kh][kw]
__device__ alignas(16) unsigned short g_Wt[9*64*64];

__global__ void wt_kernel(const float* __restrict__ w){
  int t = blockIdx.x*256 + threadIdx.x;          // 36864 total
  if (t >= 9*64*64) return;
  int ci = t & 63, o = (t >> 6) & 63, tap = t >> 12;
  int kh = tap/3, kw = tap%3;
  g_Wt[t] = f2bf(w[((o*64 + ci)*3 + kh)*3 + kw]);
}

// double-row slab: [66 cols][2 rows][64 ci] bf16 -> 256B col-stride
// swizzle: (full byte offset within slab) ^ ((c&15)<<4)
#define DSLAB 16896

__global__ __launch_bounds__(256, 2) void conv_main(const float* __restrict__ x,
                                                    const float* __restrict__ bias,
                                                    float* __restrict__ out){
  __shared__ alignas(16) char smem[3*DSLAB];
  const int n0 = blockIdx.x*64, y0 = blockIdx.y*16, b = blockIdx.z;
  const int rows  = min(16, 254 - y0);           // 16, or 14 for last strip (always even)
  const int niter = rows >> 1;
  const int tid = threadIdx.x, lane = tid & 63, wv = tid >> 6;
  const int wr = wv >> 1, wc = wv & 1;
  const float* xb = x + (size_t)b*64*65536;

  // hoisted A fragments (compiler may rematerialize from L1; both fine)
  s16x8 aw[36];
  {
    const int o = wr*32 + (lane & 31);
    const int cib = (lane >> 5) * 8;
    #pragma unroll
    for (int tap = 0; tap < 9; ++tap)
      #pragma unroll
      for (int part = 0; part < 4; ++part)
        aw[tap*4+part] = *reinterpret_cast<const s16x8*>(
            &g_Wt[(tap*64 + o)*64 + part*16 + cib]);
  }

  // bias per C/D row map: o = wr*32 + 4*(lane>>5) + (reg&3)+8*(reg>>2)
  const int ob = wr*32 + 4*(lane >> 5);
  float bv[16];
  #pragma unroll
  for (int reg = 0; reg < 16; ++reg)
    bv[reg] = bias[ob + (reg & 3) + 8*(reg >> 2)];

  // ---- prologue: stage rows y0..y0+3 into dslabs 0,1 ----
  #pragma unroll
  for (int d = 0; d < 2; ++d){
    const int rr = y0 + 2*d;
    #pragma unroll
    for (int it = 0; it < 3; ++it){
      int tau = it*256 + tid;
      if (tau < 544){
        int cp = tau & 31, q = tau >> 5, c0 = q*4;
        int cg = n0 + c0; if (cg > 252) cg = 252;   // only q=16 clamps; feeds discarded n>=254
        const float* p = xb + (size_t)(2*cp)*65536 + rr*256 + cg;
        float4 v00 = *reinterpret_cast<const float4*>(p);
        float4 v01 = *reinterpret_cast<const float4*>(p + 65536);
        float4 v10 = *reinterpret_cast<const float4*>(p + 256);
        float4 v11 = *reinterpret_cast<const float4*>(p + 65536 + 256);
        const float* a00 = (const float*)&v00; const float* a01 = (const float*)&v01;
        const float* a10 = (const float*)&v10; const float* a11 = (const float*)&v11;
        #pragma unroll
        for (int j = 0; j < 4; ++j){
          int c = c0 + j;
          if (c < 66){
            unsigned pk0 = (unsigned)f2bf(a00[j]) | ((unsigned)f2bf(a01[j]) << 16);
            unsigned pk1 = (unsigned)f2bf(a10[j]) | ((unsigned)f2bf(a11[j]) << 16);
            int swz = (c & 15) << 4;
            int base = c*256 + cp*4;
            *(unsigned*)(smem + d*DSLAB + ((base      ) ^ swz)) = pk0;  // even row (p=0)
            *(unsigned*)(smem + d*DSLAB + ((base + 128) ^ swz)) = pk1;  // odd row  (p=1)
          }
        }
      }
    }
  }
  __syncthreads();

  // ---- main loop: row pairs, ring of 3 double-slabs ----
  int d0 = 0;
  for (int t = 0; t < niter; ++t){
    const int y = y0 + 2*t;
    const int d1 = (d0 + 1 > 2) ? 0 : d0 + 1;
    const int d2 = 3 - d0 - d1;

    // T14 issue-early: rows y+4, y+5 for dslab d2 (consumed next iter)
    float4 pf[3][4];
    const bool hav = (t + 1 < niter);
    if (hav){
      const int rr = y + 4;                       // rr+1 <= 255 by strip geometry
      #pragma unroll
      for (int it = 0; it < 3; ++it){
        int tau = it*256 + tid;
        if (tau < 544){
          int cp = tau & 31, q = tau >> 5;
          int cg = n0 + q*4; if (cg > 252) cg = 252;
          const float* p = xb + (size_t)(2*cp)*65536 + rr*256 + cg;
          pf[it][0] = *reinterpret_cast<const float4*>(p);
          pf[it][1] = *reinterpret_cast<const float4*>(p + 65536);
          pf[it][2] = *reinterpret_cast<const float4*>(p + 256);
          pf[it][3] = *reinterpret_cast<const float4*>(p + 65536 + 256);
        }
      }
    }

    // compute output rows y, y+1 (both always valid: rows is even)
    f32x16 acc[2];
    #pragma unroll
    for (int r = 0; r < 2; ++r)
      #pragma unroll
      for (int i = 0; i < 16; ++i) acc[r][i] = 0.f;

    #pragma unroll
    for (int kh = 0; kh < 3; ++kh){
      #pragma unroll
      for (int row = 0; row < 2; ++row){
        const int lrr = kh + row;                 // input row offset from y
        const int dd = (lrr >> 1) ? d1 : d0;
        const int pp = lrr & 1;
        const char* slab = smem + dd*DSLAB;
        #pragma unroll
        for (int kw = 0; kw < 3; ++kw){
          const int c = wc*32 + (lane & 31) + kw;
          const int swz = (c & 15) << 4;
          const int cb = c*256 + pp*128 + ((lane >> 5) << 4);
          #pragma unroll
          for (int part = 0; part < 4; ++part){
            s16x8 bf = *reinterpret_cast<const s16x8*>(
                slab + ((cb + part*32) ^ swz));
            acc[row] = __builtin_amdgcn_mfma_f32_32x32x16_bf16(
                aw[(kh*3+kw)*4 + part], bf, acc[row], 0, 0, 0);
          }
        }
      }
    }

    // stores
    const int nl = n0 + wc*32 + (lane & 31);
    if (nl < 254){
      #pragma unroll
      for (int row = 0; row < 2; ++row){
        size_t rowbase = (((size_t)b*64 + ob)*254 + (y + row))*254 + nl;
        #pragma unroll
        for (int reg = 0; reg < 16; ++reg){
          int od = (reg & 3) + 8*(reg >> 2);
          out[rowbase + (size_t)od*64516] = acc[row][reg] + bv[reg];
        }
      }
    }

    // write-late: cvt + ds_write rows y+4,y+5 into dslab d2
    if (hav){
      #pragma unroll
      for (int it = 0; it < 3; ++it){
        int tau = it*256 + tid;
        if (tau < 544){
          int cp = tau & 31, q = tau >> 5, c0 = q*4;
          const float* a00 = (const float*)&pf[it][0];
          const float* a01 = (const float*)&pf[it][1];
          const float* a10 = (const float*)&pf[it][2];
          const float* a11 = (const float*)&pf[it][3];
          #pragma unroll
          for (int j = 0; j < 4; ++j){
            int c = c0 + j;
            if (c < 66){
              unsigned pk0 = (unsigned)f2bf(a00[j]) | ((unsigned)f2bf(a01[j]) << 16);
              unsigned pk1 = (unsigned)f2bf(a10[j]) | ((unsigned)f2bf(a11[j]) << 16);
              int swz = (c & 15) << 4;
              int base = c*256 + cp*4;
              *(unsigned*)(smem + d2*DSLAB + ((base      ) ^ swz)) = pk0;
              *(unsigned*)(smem + d2*DSLAB + ((base + 128) ^ swz)) = pk1;
            }
          }
        }
      }
    }
    __syncthreads();
    d0 = d1;
  }
}

extern "C" void kernel_launch(void* const* d_in, const int* in_sizes, int n_in,
                              void* d_out, int out_size, void* d_ws, size_t ws_size,
                              hipStream_t stream) {
  const float* x    = (const float*)d_in[0];
  const float* wgt  = (const float*)d_in[1];
  const float* bias = (const float*)d_in[2];
  float* out = (float*)d_out;

  wt_kernel<<<144, 256, 0, stream>>>(wgt);
  conv_main<<<dim3(4, 16, 8), 256, 0, stream>>>(x, bias, out);
}